// Round 2
// baseline (364.225 us; speedup 1.0000x reference)
//
#include <hip/hip_runtime.h>
#include <math.h>

// LinkedCrossEntropy: mean over B of penalty * weight[y] * NLL
//   B = 65536, C = 1000
//   penalty = 2.0 if (argmax(y_pred[i]) != y_true[i]) && link[y_true[i]][pred] else 1.0
//   NLL = logsumexp(y_pred[i]) - y_pred[i][y_true[i]]
//
// Memory-bound: y_pred = 262 MB fp32 read once. One wave per sample,
// 250 float4 per row (coalesced), register-resident two-pass softmax stats,
// width-64 butterfly reduce, one atomicAdd per block.
//
// R1 post-mortem: link_matrix (jnp.bool_) is delivered by the harness as
// int32 ("integer -> const int*"), NOT as 1-byte bools. Reading it as bytes
// made penalty=2 fire w.p. 1/8 instead of 1/2 -> absmax 1.375 = 5.5 * 0.25,
// an exact match. Fix: gather as int32.

#define B_SAMPLES 65536
#define C_CLASSES 1000
#define C4 250  // float4 chunks per row (1000 floats)

__global__ __launch_bounds__(256) void lce_kernel(
    const float* __restrict__ y_pred,
    const int* __restrict__ y_true,
    const float* __restrict__ weight,
    const int* __restrict__ link,  // bool matrix delivered as int32
    float* __restrict__ out)
{
    const int lane = threadIdx.x & 63;
    const int wave = threadIdx.x >> 6;
    const int gwave = blockIdx.x * 4 + wave;
    const int nwaves = gridDim.x * 4;

    float local = 0.0f;

    for (int s = gwave; s < B_SAMPLES; s += nwaves) {
        const float4* row = (const float4*)(y_pred + (size_t)s * C_CLASSES);

        // ---- load 16 elements/lane into registers (tail padded -inf) ----
        float4 v[4];
        #pragma unroll
        for (int it = 0; it < 4; ++it) {
            int idx = it * 64 + lane;
            if (idx < C4) {
                v[it] = row[idx];
            } else {
                v[it] = make_float4(-INFINITY, -INFINITY, -INFINITY, -INFINITY);
            }
        }

        // ---- pass 1: per-lane max + argmax (first occurrence) ----
        float m = -INFINITY;
        int am = 0;
        #pragma unroll
        for (int it = 0; it < 4; ++it) {
            const float* p = (const float*)&v[it];
            #pragma unroll
            for (int j = 0; j < 4; ++j) {
                float x = p[j];
                int col = (it * 64 + lane) * 4 + j;
                if (x > m) { m = x; am = col; }
            }
        }

        // ---- pass 2: sum of exp(x - m); padded -inf contributes 0 ----
        float sum = 0.0f;
        #pragma unroll
        for (int it = 0; it < 4; ++it) {
            const float* p = (const float*)&v[it];
            #pragma unroll
            for (int j = 0; j < 4; ++j) {
                sum += __expf(p[j] - m);
            }
        }

        // ---- width-64 butterfly reduce of (m, sum, am) ----
        #pragma unroll
        for (int off = 32; off > 0; off >>= 1) {
            float om  = __shfl_xor(m, off, 64);
            float os  = __shfl_xor(sum, off, 64);
            int   oam = __shfl_xor(am, off, 64);
            float M = fmaxf(m, om);
            sum = sum * __expf(m - M) + os * __expf(om - M);
            am = (om > m || (om == m && oam < am)) ? oam : am;
            m = M;
        }

        // ---- per-sample scalar epilogue on lane 0 ----
        if (lane == 0) {
            int t = y_true[s];
            float xt = y_pred[(size_t)s * C_CLASSES + t];
            float nll = m + __logf(sum) - xt;
            float pen = (am != t && link[(size_t)t * C_CLASSES + am] != 0)
                            ? 2.0f : 1.0f;
            local += pen * weight[t] * nll;
        }
    }

    // ---- block reduce (lane 0 of each of the 4 waves) + one atomic ----
    __shared__ float wsum[4];
    if (lane == 0) wsum[wave] = local;
    __syncthreads();
    if (threadIdx.x == 0) {
        float total = (wsum[0] + wsum[1] + wsum[2] + wsum[3]) * (1.0f / B_SAMPLES);
        atomicAdd(out, total);
    }
}

extern "C" void kernel_launch(void* const* d_in, const int* in_sizes, int n_in,
                              void* d_out, int out_size, void* d_ws, size_t ws_size,
                              hipStream_t stream) {
    const float* y_pred = (const float*)d_in[0];
    const int* y_true   = (const int*)d_in[1];
    const float* weight = (const float*)d_in[2];
    const int* link     = (const int*)d_in[3];
    float* out          = (float*)d_out;

    // Harness poisons d_out with 0xAA before every timed launch — zero it.
    hipMemsetAsync(out, 0, sizeof(float), stream);

    // 2048 blocks x 256 threads = 8192 waves -> 8 samples per wave.
    lce_kernel<<<2048, 256, 0, stream>>>(y_pred, y_true, weight, link, out);
}